// Round 7
// baseline (3851.473 us; speedup 1.0000x reference)
//
#include <hip/hip_runtime.h>
#include <cstddef>
#include <cstdint>

// LSTM_27934467293427 — R11: single-wave k2 (zero barriers) via mixed-A-row MFMA.
// R9/R10 fused dispatch failed twice at container level; retreat to separate
// launches (known-safe) and attack the ~400-600cy/step barrier+wakeup cost that
// three different k2 structures all paid: ONE wave per block needs no barrier.
// Trick: A rows 0-7 = h_hi, rows 8-15 = h_lo; acc += mfma(A,Bh)+mfma(A,Bl);
// then D[0]+D[8] = (Ah+Al)(Bh+Bl) — FULL split (tighter than R7) at 2 MFMAs
// per (tile,kc) + one shfl_xor(.,32) (D rows 0/8 sit in quads q / q^2).
// Lane l owns col l; tile select by (quad&1) so shuffle partners agree.
// Weights: Bh+Bl 256 VGPR + head 16; launch_bounds(64,1) -> ~512 budget.
// K1 (gx = X·Wih^T + bias, split-bf16 MFMA) unchanged from R8.

namespace {

constexpr int B_ = 256, S_ = 2048, E_ = 128, H_ = 64, G_ = 256, H2_ = 2;

typedef short short8 __attribute__((ext_vector_type(8)));
typedef float f4 __attribute__((ext_vector_type(4)));

__device__ __forceinline__ float sigm(float x) {
    return __builtin_amdgcn_rcpf(1.0f + __expf(-x));
}
__device__ __forceinline__ float tanh_fast(float x) {
    return 1.0f - 2.0f * __builtin_amdgcn_rcpf(1.0f + __expf(2.0f * x));
}
__device__ __forceinline__ short f2bf(float f) {  // RNE float->bf16
    union { float f; uint32_t u; } a; a.f = f;
    uint32_t r = a.u + 0x7FFFu + ((a.u >> 16) & 1u);
    return (short)(r >> 16);
}
__device__ __forceinline__ float bf2f(short s) {
    union { uint32_t u; float f; } a; a.u = ((uint32_t)(uint16_t)s) << 16;
    return a.f;
}
// packed RNE f32x2 -> bf16x2 (src0 -> low16, src1 -> high16)
__device__ __forceinline__ uint32_t cvtpk(float a, float b) {
    uint32_t r;
    asm("v_cvt_pk_bf16_f32 %0, %1, %2" : "=v"(r) : "v"(a), "v"(b));
    return r;
}
__device__ __forceinline__ void cvt8(float4 a, float4 b, short8& hi, short8& lo) {
    float v[8] = {a.x, a.y, a.z, a.w, b.x, b.y, b.z, b.w};
    uint32_t* hp = (uint32_t*)&hi;
    uint32_t* lp = (uint32_t*)&lo;
    #pragma unroll
    for (int i = 0; i < 4; ++i) {
        const uint32_t h = cvtpk(v[2 * i], v[2 * i + 1]);
        union { uint32_t u; float f; } f0, f1;
        f0.u = h << 16;            // bf2f of low element
        f1.u = h & 0xffff0000u;    // bf2f of high element
        lp[i] = cvtpk(v[2 * i] - f0.f, v[2 * i + 1] - f1.f);
        hp[i] = h;
    }
}

// ---------------- K1: gx[b][tau][j] = sum_e x[b,cs+tau,e]*Wih[j,e] + bias[j] ----
__global__ __launch_bounds__(256) void k1_gemm(
    const float* __restrict__ x, const int* __restrict__ lengths,
    const float* __restrict__ Wih, const float* __restrict__ bih,
    const float* __restrict__ bhh, float* __restrict__ gx, int cs, int tcLog)
{
    const int Tc = 1 << tcLog;
    const int t = threadIdx.x;
    const int lane = t & 63, wv = t >> 6;
    const int lm = lane & 15, quad = lane >> 4;
    const int nbase = blockIdx.y * 128 + wv * 32;
    const int rowblk = blockIdx.x * 128;

    short8 Bh[2][4], Bl[2][4];
    float bias[2];
    #pragma unroll
    for (int nt = 0; nt < 2; ++nt) {
        const int n = nbase + nt * 16 + lm;
        bias[nt] = bih[n] + bhh[n];
        #pragma unroll
        for (int kk = 0; kk < 4; ++kk) {
            const float4* wp = (const float4*)(Wih + n * E_ + kk * 32 + quad * 8);
            cvt8(wp[0], wp[1], Bh[nt][kk], Bl[nt][kk]);
        }
    }

    for (int slab = 0; slab < 8; ++slab) {
        const int row0 = rowblk + slab * 16;
        const int b = row0 >> tcLog;
        const int tb = row0 & (Tc - 1);
        int len = lengths[b]; len = len < 1 ? 1 : (len > S_ ? S_ : len);
        if (cs + tb >= len) continue;

        const float* xr = x + ((size_t)b * S_ + cs + tb + lm) * E_;
        short8 Ah[4], Al[4];
        #pragma unroll
        for (int kk = 0; kk < 4; ++kk) {
            const float4* ap = (const float4*)(xr + kk * 32 + quad * 8);
            cvt8(ap[0], ap[1], Ah[kk], Al[kk]);
        }
        f4 acc[2] = {{0,0,0,0},{0,0,0,0}};
        #pragma unroll
        for (int kk = 0; kk < 4; ++kk) {
            #pragma unroll
            for (int nt = 0; nt < 2; ++nt) {
                acc[nt] = __builtin_amdgcn_mfma_f32_16x16x32_bf16(Ah[kk], Bh[nt][kk], acc[nt], 0, 0, 0);
                acc[nt] = __builtin_amdgcn_mfma_f32_16x16x32_bf16(Al[kk], Bh[nt][kk], acc[nt], 0, 0, 0);
                acc[nt] = __builtin_amdgcn_mfma_f32_16x16x32_bf16(Ah[kk], Bl[nt][kk], acc[nt], 0, 0, 0);
            }
        }
        float* gp = gx + ((size_t)b * Tc + tb) * G_;
        #pragma unroll
        for (int nt = 0; nt < 2; ++nt) {
            #pragma unroll
            for (int r = 0; r < 4; ++r) {
                gp[(quad * 4 + r) * G_ + nbase + nt * 16 + lm] = acc[nt][r] + bias[nt];
            }
        }
    }
}

// ---------------- K2: single-wave MFMA recurrence, grid(B), block(64) ---------
__global__ __launch_bounds__(64, 1) void k2_recur(
    const float* __restrict__ gx, const int* __restrict__ lengths,
    const float* __restrict__ Whh, const float* __restrict__ hWih,
    const float* __restrict__ hWhh, const float* __restrict__ hbih,
    const float* __restrict__ hbhh, float* __restrict__ out,
    float* __restrict__ stH, float* __restrict__ stC, float* __restrict__ stHK,
    int cs, int Tc)
{
    const int b = blockIdx.x, lane = threadIdx.x;
    const int lm = lane & 15, quad = lane >> 4;
    int len = lengths[b]; len = len < 1 ? 1 : (len > S_ ? S_ : len);
    if (cs > len) return;
    const int ce = cs + Tc;

    // h as bf16 hi/lo, double-buffered: [parity][hi=0/lo=1][col]
    __shared__ __align__(16) unsigned short hbuf[2][2][H_];

    // Gate weights: 16 (gate,coltile) B-frags, hi+lo. col of tile = lm.
    short8 Bh[4][4][2], Bl[4][4][2];   // [gate][ct][kc]
    #pragma unroll
    for (int g = 0; g < 4; ++g) {
        #pragma unroll
        for (int ct = 0; ct < 4; ++ct) {
            const int n = g * 64 + ct * 16 + lm;
            #pragma unroll
            for (int kc = 0; kc < 2; ++kc) {
                const float4* wp = (const float4*)(Whh + (size_t)n * H_ + kc * 32 + quad * 8);
                cvt8(wp[0], wp[1], Bh[g][ct][kc], Bl[g][ct][kc]);
            }
        }
    }

    // Head weights (plain bf16 hi; h-split still captured via mixed A rows).
    short8 KB[2][2];
    {
        short8 junk;
        #pragma unroll
        for (int kc = 0; kc < 2; ++kc) {
            const float4* kp = (const float4*)(hWih + (size_t)lm * H_ + kc * 32 + quad * 8);
            cvt8(kp[0], kp[1], KB[0][kc], junk);
        }
        if (lm < 10) {
            #pragma unroll
            for (int kc = 0; kc < 2; ++kc) {
                const float4* kp = (const float4*)(hWih + (size_t)(16 + lm) * H_ + kc * 32 + quad * 8);
                cvt8(kp[0], kp[1], KB[1][kc], junk);
            }
        } else {
            #pragma unroll
            for (int kc = 0; kc < 2; ++kc) KB[1][kc] = (short8)(short)0;
        }
    }
    const int rown = (quad & 1) * 16 + lm;          // head row owned by quads 0,1
    const bool hOwn = (quad < 2) && (rown < 26);
    float hbz = 0.f, w0 = 0.f, w1 = 0.f;
    if (hOwn) {
        hbz = hbih[rown] + hbhh[rown];
        w0 = hWhh[rown * 2 + 0];
        w1 = hWhh[rown * 2 + 1];
    }

    // ---- state init / restore (lane owns col = lane) ----
    float c = 0.f, h = 0.f, hk = 0.f;
    if (cs == 0) {
        hbuf[0][0][lane] = 0;
        hbuf[0][1][lane] = 0;
    } else {
        h = stH[b * 64 + lane];
        c = stC[b * 64 + lane];
        const uint32_t hh = cvtpk(h, 0.f);
        union { uint32_t u; float f; } hf; hf.u = hh << 16;
        const uint32_t ll = cvtpk(h - hf.f, 0.f);
        hbuf[cs & 1][0][lane] = (unsigned short)(hh & 0xffffu);
        hbuf[cs & 1][1][lane] = (unsigned short)(ll & 0xffffu);
        if (hOwn) hk = stHK[b * 32 + rown];
    }
    // single wave: DS pipe in-order — no barrier anywhere.

    // ---- gx prefetch (distance 2); lane reads cols g*64 + lane ----
    const float* gxp = gx + (size_t)b * Tc * G_ + lane;
    float ga0 = 0.f, ga1 = 0.f, ga2 = 0.f, ga3 = 0.f;
    float gb0 = 0.f, gb1 = 0.f, gb2 = 0.f, gb3 = 0.f;
    if (cs < len) { ga0 = gxp[0]; ga1 = gxp[64]; ga2 = gxp[128]; ga3 = gxp[192]; }
    if (cs + 1 < len && cs + 1 < ce) {
        const float* r = gxp + G_;
        gb0 = r[0]; gb1 = r[64]; gb2 = r[128]; gb3 = r[192];
    }

    for (int u = cs; u < ce; ++u) {
        // A-frags: rows 0-7 (lanes lm<8) = h_hi, rows 8-15 = h_lo. Broadcast
        // reads: 8 lanes share each address; hi/lo pairs are 2-way (free).
        const unsigned short* src = (lm < 8) ? &hbuf[u & 1][0][0] : &hbuf[u & 1][1][0];
        const short8 A0 = *(const short8*)(src + quad * 8);
        const short8 A1 = *(const short8*)(src + 32 + quad * 8);

        // head: z tiles (4 MFMAs into 2 accs)
        f4 hz0 = {0,0,0,0}, hz1 = {0,0,0,0};
        hz0 = __builtin_amdgcn_mfma_f32_16x16x32_bf16(A0, KB[0][0], hz0, 0, 0, 0);
        hz1 = __builtin_amdgcn_mfma_f32_16x16x32_bf16(A0, KB[1][0], hz1, 0, 0, 0);
        hz0 = __builtin_amdgcn_mfma_f32_16x16x32_bf16(A1, KB[0][1], hz0, 0, 0, 0);
        hz1 = __builtin_amdgcn_mfma_f32_16x16x32_bf16(A1, KB[1][1], hz1, 0, 0, 0);
        if (u >= 1) {
            const float s0 = hz0[0], s1 = hz1[0];
            const float zv0 = s0 + __shfl_xor(s0, 32);   // hi-part + lo-part
            const float zv1 = s1 + __shfl_xor(s1, 32);
            const float z = (quad & 1) ? zv1 : zv0;
            const float p = __shfl_xor(hk, 1);
            const float e0 = (lm & 1) ? p : hk;
            const float e1 = (lm & 1) ? hk : p;
            const float hkn = tanh_fast(z + hbz + w0 * e0 + w1 * e1);
            if (quad < 2) hk = hkn;
            if (u == len) {     // uniform: single wave exits together
                if (hOwn) out[((rown >> 1) * B_ + b) * H2_ + (rown & 1)] = sigm(hk);
                return;
            }
        }

        // gates: 16 groups × 4 MFMAs (Bh+Bl over 2 kc) into one acc each;
        // D[0]+D[8] (via shfl_xor 32) = (Ah+Al)(Bh+Bl).
        float s[4][4];
        #pragma unroll
        for (int g = 0; g < 4; ++g) {
            #pragma unroll
            for (int ct = 0; ct < 4; ++ct) {
                f4 a = {0,0,0,0};
                a = __builtin_amdgcn_mfma_f32_16x16x32_bf16(A0, Bh[g][ct][0], a, 0, 0, 0);
                a = __builtin_amdgcn_mfma_f32_16x16x32_bf16(A0, Bl[g][ct][0], a, 0, 0, 0);
                a = __builtin_amdgcn_mfma_f32_16x16x32_bf16(A1, Bh[g][ct][1], a, 0, 0, 0);
                a = __builtin_amdgcn_mfma_f32_16x16x32_bf16(A1, Bl[g][ct][1], a, 0, 0, 0);
                s[g][ct] = a[0];
            }
        }
        float v0, v1, v2, v3;
        {
            // lane's col = lane; tile = quad; partner (quad^2) extracts the
            // same (quad&1)-selected tiles, so the shuffle sums hi+lo rows.
            #pragma unroll
            for (int g = 0; g < 4; ++g) {
                const float sA = (quad & 1) ? s[g][1] : s[g][0];
                const float sB = (quad & 1) ? s[g][3] : s[g][2];
                const float vA = sA + __shfl_xor(sA, 32);
                const float vB = sB + __shfl_xor(sB, 32);
                const float vv = (quad >> 1) ? vB : vA;
                if (g == 0) v0 = vv + ga0;
                else if (g == 1) v1 = vv + ga1;
                else if (g == 2) v2 = vv + ga2;
                else v3 = vv + ga3;
            }
        }
        c = sigm(v1) * c + sigm(v0) * tanh_fast(v2);
        h = sigm(v3) * tanh_fast(c);
        {
            const uint32_t hh = cvtpk(h, 0.f);
            union { uint32_t u; float f; } hf; hf.u = hh << 16;
            const uint32_t ll = cvtpk(h - hf.f, 0.f);
            hbuf[(u + 1) & 1][0][lane] = (unsigned short)(hh & 0xffffu);
            hbuf[(u + 1) & 1][1][lane] = (unsigned short)(ll & 0xffffu);
        }
        ga0 = gb0; ga1 = gb1; ga2 = gb2; ga3 = gb3;
        const int un = u + 2;
        if (un < len && un < ce) {
            const float* r = gxp + (size_t)(un - cs) * G_;
            gb0 = r[0]; gb1 = r[64]; gb2 = r[128]; gb3 = r[192];
        } else {
            gb0 = gb1 = gb2 = gb3 = 0.f;
        }
    }

    // chunk complete (len >= ce): persist state
    stH[b * 64 + lane] = h;
    stC[b * 64 + lane] = c;
    if (hOwn) stHK[b * 32 + rown] = hk;

    if (ce == S_ && len == S_) {
        // lagged final head for h_{S-1} (written at u=S-1 to parity S&1 = 0)
        const unsigned short* src = (lm < 8) ? &hbuf[S_ & 1][0][0] : &hbuf[S_ & 1][1][0];
        const short8 A0 = *(const short8*)(src + quad * 8);
        const short8 A1 = *(const short8*)(src + 32 + quad * 8);
        f4 hz0 = {0,0,0,0}, hz1 = {0,0,0,0};
        hz0 = __builtin_amdgcn_mfma_f32_16x16x32_bf16(A0, KB[0][0], hz0, 0, 0, 0);
        hz1 = __builtin_amdgcn_mfma_f32_16x16x32_bf16(A0, KB[1][0], hz1, 0, 0, 0);
        hz0 = __builtin_amdgcn_mfma_f32_16x16x32_bf16(A1, KB[0][1], hz0, 0, 0, 0);
        hz1 = __builtin_amdgcn_mfma_f32_16x16x32_bf16(A1, KB[1][1], hz1, 0, 0, 0);
        const float s0 = hz0[0], s1 = hz1[0];
        const float zv0 = s0 + __shfl_xor(s0, 32);
        const float zv1 = s1 + __shfl_xor(s1, 32);
        const float z = (quad & 1) ? zv1 : zv0;
        const float p = __shfl_xor(hk, 1);
        const float e0 = (lm & 1) ? p : hk;
        const float e1 = (lm & 1) ? hk : p;
        const float hkn = tanh_fast(z + hbz + w0 * e0 + w1 * e1);
        if (hOwn) out[((rown >> 1) * B_ + b) * H2_ + (rown & 1)] = sigm(hkn);
    }
}

}  // namespace

extern "C" void kernel_launch(void* const* d_in, const int* in_sizes, int n_in,
                              void* d_out, int out_size, void* d_ws, size_t ws_size,
                              hipStream_t stream) {
    const float* x    = (const float*)d_in[0];
    const int*   len  = (const int*)d_in[1];
    const float* Wih  = (const float*)d_in[2];
    const float* Whh  = (const float*)d_in[3];
    const float* bih  = (const float*)d_in[4];
    const float* bhh  = (const float*)d_in[5];
    const float* hWih = (const float*)d_in[6];
    const float* hWhh = (const float*)d_in[7];
    const float* hbih = (const float*)d_in[8];
    const float* hbhh = (const float*)d_in[9];
    float* out = (float*)d_out;

    // pick chunk length fitting the workspace (gx chunk + 160KB state)
    int tcLog = 8;  // Tc = 256
    while (tcLog > 5) {
        size_t need = (size_t)B_ * ((size_t)1 << tcLog) * G_ * 4 + 160 * 1024;
        if (need <= ws_size) break;
        --tcLog;
    }
    const int Tc = 1 << tcLog;
    float* gxbuf = (float*)d_ws;
    size_t gxBytes = (size_t)B_ * Tc * G_ * 4;
    float* stH  = (float*)((char*)d_ws + gxBytes);
    float* stC  = stH + B_ * 64;
    float* stHK = stC + B_ * 64;   // B*32 floats used

    for (int cs = 0; cs < S_; cs += Tc) {
        dim3 g1(B_ * Tc / 128, 2);
        hipLaunchKernelGGL(k1_gemm, g1, dim3(256), 0, stream,
                           x, len, Wih, bih, bhh, gxbuf, cs, tcLog);
        hipLaunchKernelGGL(k2_recur, dim3(B_), dim3(64), 0, stream,
                           gxbuf, len, Whh, hWih, hWhh, hbih, hbhh, out,
                           stH, stC, stHK, cs, Tc);
    }
}